// Round 1
// baseline (262.850 us; speedup 1.0000x reference)
//
#include <hip/hip_runtime.h>

// YOLO-v1 style loss on MI355X.
// Inputs: d_in[0] = output (BATCH*S*S*30 fp32), d_in[1] = target (same).
// Outputs: d_out[0..2] = (loss, sum_iou, acc) as fp32.
//
// Memory-bound: 96.3 MB input -> ~15 us HBM floor at 6.3 TB/s.

#define NACC 8
// ws layout: [0]=n_obj [1]=contain_num [2]=obj_num [3]=notcontain_num
//            [4]=noobj_num [5]=class_num [6]=sum_iou [7]=acc

__device__ __forceinline__ float wave_reduce_sum(float v) {
    #pragma unroll
    for (int off = 32; off > 0; off >>= 1)
        v += __shfl_down(v, off, 64);
    return v;
}

__global__ __launch_bounds__(256) void yolo_loss_kernel(
        const float* __restrict__ out,
        const float* __restrict__ tgt,
        float* __restrict__ ws, int N) {
    const int i = blockIdx.x * blockDim.x + threadIdx.x;

    float v[NACC];
    #pragma unroll
    for (int k = 0; k < NACC; k++) v[k] = 0.f;

    if (i < N) {
        const float* o = out + (size_t)i * 30;
        const float* t = tgt + (size_t)i * 30;
        float ov[30], tv[30];
        #pragma unroll
        for (int k = 0; k < 30; k++) { ov[k] = o[k]; tv[k] = t[k]; }

        const float m = (tv[4] > 0.f) ? 1.f : 0.f;

        // target corners (xy/S +- 0.5*wh), matching reference arithmetic
        const float tx0 = tv[0] / 7.f - 0.5f * tv[2];
        const float ty0 = tv[1] / 7.f - 0.5f * tv[3];
        const float tx1 = tv[0] / 7.f + 0.5f * tv[2];
        const float ty1 = tv[1] / 7.f + 0.5f * tv[3];
        const float at  = (tx1 - tx0) * (ty1 - ty0);

        float iou[2];
        #pragma unroll
        for (int b = 0; b < 2; b++) {
            const float* pb = ov + b * 5;
            const float px0 = pb[0] / 7.f - 0.5f * pb[2];
            const float py0 = pb[1] / 7.f - 0.5f * pb[3];
            const float px1 = pb[0] / 7.f + 0.5f * pb[2];
            const float py1 = pb[1] / 7.f + 0.5f * pb[3];
            const float ap  = (px1 - px0) * (py1 - py0);
            const float ulx = fmaxf(px0, tx0), uly = fmaxf(py0, ty0);
            const float lrx = fminf(px1, tx1), lry = fminf(py1, ty1);
            const float wi  = fmaxf(lrx - ulx, 0.f);
            const float hi  = fmaxf(lry - uly, 0.f);
            const float inter = wi * hi;
            iou[b] = inter / (ap + at - inter);
        }

        // argmax with first-max tie-break: resp=1 only if strictly greater
        const int resp = (iou[1] > iou[0]) ? 1 : 0;
        const float max_iou = fmaxf(iou[0], iou[1]);
        const float min_iou = fminf(iou[0], iou[1]);
        const float* rb = ov + resp * 5;
        const float* nb = ov + (1 - resp) * 5;

        // contain: xy L2 + sqrt(wh) L2 on the responsible box
        {
            const float dx = rb[0] - tv[0];
            const float dy = rb[1] - tv[1];
            const float dw = sqrtf(rb[2]) - sqrtf(tv[2]);
            const float dh = sqrtf(rb[3]) - sqrtf(tv[3]);
            v[1] = m * (dx * dx + dy * dy + dw * dw + dh * dh);
        }
        {
            const float d = rb[4] - max_iou;
            v[2] = m * d * d;
        }
        v[3] = m * nb[4] * nb[4];
        {
            const float d0 = ov[4] - tv[4];
            const float d1 = ov[9] - tv[9];
            v[4] = (1.f - m) * (d0 * d0 + d1 * d1);
        }

        // class loss + argmax accuracy (first-max semantics via strict >)
        float cls_sum = 0.f;
        int oarg = 0, targ = 0;
        float obest = ov[10], tbest = tv[10];
        #pragma unroll
        for (int c = 0; c < 20; c++) {
            const float oc = ov[10 + c], tc = tv[10 + c];
            const float d = oc - tc;
            cls_sum += d * d;
            if (oc > obest) { obest = oc; oarg = c; }
            if (tc > tbest) { tbest = tc; targ = c; }
        }
        v[5] = m * cls_sum;
        v[6] = m * min_iou;
        v[7] = (m > 0.f && oarg == targ) ? 1.f : 0.f;
        v[0] = m;
    }

    // wave reduce -> LDS block reduce -> one atomicAdd set per block
    __shared__ float sred[4][NACC];
    const int lane = threadIdx.x & 63;
    const int wid  = threadIdx.x >> 6;
    #pragma unroll
    for (int k = 0; k < NACC; k++) v[k] = wave_reduce_sum(v[k]);
    if (lane == 0) {
        #pragma unroll
        for (int k = 0; k < NACC; k++) sred[wid][k] = v[k];
    }
    __syncthreads();
    if (threadIdx.x == 0) {
        #pragma unroll
        for (int k = 0; k < NACC; k++) {
            const float s = sred[0][k] + sred[1][k] + sred[2][k] + sred[3][k];
            atomicAdd(&ws[k], s);
        }
    }
}

__global__ void yolo_finalize_kernel(const float* __restrict__ ws,
                                     float* __restrict__ out, int N) {
    const float n_obj   = ws[0];
    const float n_noobj = (float)N - n_obj;
    const float contain     = ws[1] / (2.f * n_obj);
    const float obj_loss    = ws[2] / n_obj;
    const float not_contain = ws[3] / n_obj;
    const float noobj_loss  = ws[4] / (2.f * n_noobj);
    const float class_loss  = ws[5] / (n_obj * 20.f);
    const float loss = 5.f * contain + obj_loss
                     + 0.5f * (noobj_loss + not_contain) + class_loss;
    out[0] = loss;
    out[1] = ws[6];
    out[2] = ws[7];
}

extern "C" void kernel_launch(void* const* d_in, const int* in_sizes, int n_in,
                              void* d_out, int out_size, void* d_ws, size_t ws_size,
                              hipStream_t stream) {
    const float* out_p = (const float*)d_in[0];
    const float* tgt_p = (const float*)d_in[1];
    float* ws  = (float*)d_ws;
    float* res = (float*)d_out;
    const int N = in_sizes[0] / 30;  // 8192*7*7 = 401408 cells

    hipMemsetAsync(ws, 0, NACC * sizeof(float), stream);
    const int block = 256;
    const int grid  = (N + block - 1) / block;
    yolo_loss_kernel<<<grid, block, 0, stream>>>(out_p, tgt_p, ws, N);
    yolo_finalize_kernel<<<1, 1, 0, stream>>>(ws, res, N);
}